// Round 9
// baseline (188.412 us; speedup 1.0000x reference)
//
#include <hip/hip_runtime.h>
#include <math.h>

// Problem constants
#define NVEC   65536      // B*H*W
#define CDIM   64
#define KBOOK  1024
#define NTOT   4194304    // B*C*H*W

// d_out layout (float32): [quantized_z: NTOT][quantized_z_st: NTOT][indices: NVEC][perplexity: 1]
// workspace: result u32[NVEC] @0 (256KB) ; float se[KBOOK] @524288 ; int hist[KBOOK] @528384
// TRANSIENT scratch in d_out's quantized_z region (read only BEFORE scatter overwrites):
//   cbT fp16[64 tiles][1024] @out+1MB (128KB) -- fragment-ordered, e scaled x2^14
//   aux @out+1.5MB: wcount u32 @+0 ; semax4 f32[4] @+16 ; se16 f32[1024] @+4096
//   wlist u32[NVEC] @out+2MB (256KB)
//   cbt  f32[64][1024] @out+2.5MB (256KB) -- TRANSPOSED codebook for rescore2
// Ordering: prep -> approx(decisive finalized) -> rescore2(flagged, exact full search)
//           -> scatter(+perp). 4 launches.
//
// ROUND-8: approx occupancy/pressure made CONSISTENT.  r7 failure: waves_per_eu(4,8)
// crushed allocation to 32 VGPR (< ~50 live) -> 1.7MB spill traffic, 70us.  Fix:
// waves_per_eu(8) (budget 64) AND single-slot loop (no ping-pong; live ~40 < 64).
// Latency hiding via TLP: grid supplies exactly 8 waves/SIMD; per-tile issue ~70cy
// x 8 waves >> 200cy L2 latency.  The r2/r4 ILP pipelines compensated for 4-wave
// occupancy; at 8 waves they are pure register-pressure cost.

typedef _Float16 f16x8 __attribute__((ext_vector_type(8)));
typedef float    f32x4 __attribute__((ext_vector_type(4)));

// prep: zero hist/wcount; exact se (pairwise 8-acc, rn intrinsics); se16 = se*2^14;
// semax4[block] = block-max of se; fragment-ordered fp16 codebook (e*2^14); cbt transpose.
__global__ void prep_kernel(const float* __restrict__ cb, float* __restrict__ se,
                            int* __restrict__ hist, _Float16* __restrict__ cbT,
                            float* __restrict__ se16, float* __restrict__ semax4,
                            unsigned* __restrict__ wcount, float* __restrict__ cbt) {
    __shared__ float lmax[4];
    const int t = blockIdx.x * 256 + threadIdx.x;   // grid 4x256 -> t = codebook row k
    if (t == 0) *wcount = 0u;
    hist[t] = 0;
    const float* row = cb + t * CDIM;
    float r[8];
#pragma unroll
    for (int j = 0; j < 8; ++j) r[j] = __fmul_rn(row[j], row[j]);
#pragma unroll
    for (int i = 8; i < 64; i += 8)
#pragma unroll
        for (int j = 0; j < 8; ++j) r[j] = __fadd_rn(r[j], __fmul_rn(row[i + j], row[i + j]));
    const float sev = __fadd_rn(__fadd_rn(__fadd_rn(r[0], r[1]), __fadd_rn(r[2], r[3])),
                                __fadd_rn(__fadd_rn(r[4], r[5]), __fadd_rn(r[6], r[7])));
    se[t] = sev;
    se16[t] = sev * 16384.0f;            // exact (x2^14)
    float m = sev;
#pragma unroll
    for (int off = 32; off > 0; off >>= 1) m = fmaxf(m, __shfl_xor(m, off));
    if ((threadIdx.x & 63) == 0) lmax[threadIdx.x >> 6] = m;
    __syncthreads();
    if (threadIdx.x == 0)
        semax4[blockIdx.x] = fmaxf(fmaxf(lmax[0], lmax[1]), fmaxf(lmax[2], lmax[3]));
    // transposed codebook for rescore2: cbt[c][k] = cb[k][c]
#pragma unroll
    for (int c = 0; c < 64; ++c) cbt[c * 1024 + t] = row[c];
    // fragment-ordered fp16 codebook, scaled: sub[lane*8+j] = fl16(e*2^14)
    const int tt = t >> 4, la = t & 15;
    _Float16* tb = cbT + (size_t)tt * 1024;        // 2KB tile block (fp16 units)
#pragma unroll
    for (int g = 0; g < 4; ++g)
#pragma unroll
        for (int j = 0; j < 8; ++j) {
            const float e0 = row[8 * g + j] * 16384.0f;        // c in [0,32)
            const float e1 = row[32 + 8 * g + j] * 16384.0f;   // c in [32,64)
            const int lo8 = (g * 16 + la) * 8 + j;             // lane*8 + j
            tb[lo8]       = (_Float16)e0;                      // ah0
            tb[512 + lo8] = (_Float16)e1;                      // ah1
        }
}

// MFMA approx + margin filter.  Wave-pair per 16-n tile: wave kh handles k-half
// [kh*512, kh*512+512) (32 tiles); exact top-2 merge across halves via LDS.
// Per-lane top-2 over its 128-k subset (packed truncated-ordered-float | k keys),
// xor-16/32 butterflies -> wave top-2, LDS merge -> global top-2.  Decisive ->
// finalize; else -> worklist.  THR: worst-case |approx-ref| bound (r5-validated).
__launch_bounds__(256)
__attribute__((amdgpu_waves_per_eu(8)))
__global__ void approx_kernel(const float* __restrict__ z, const _Float16* __restrict__ cbT,
                              const float* __restrict__ se16, const float* __restrict__ semax4,
                              unsigned* __restrict__ result, unsigned* __restrict__ wlist,
                              unsigned* __restrict__ wcount, float* __restrict__ outIdxF,
                              int* __restrict__ hist) {
    __shared__ unsigned m1[4][16], m2[4][16];
    const int tid = threadIdx.x;
    const int w = tid >> 6;           // wave in block
    const int l = tid & 63;           // lane
    const int la = l & 15;            // D-col (n) offset / A-row offset
    const int g  = l >> 4;            // lane group
    const int pair = w >> 1;          // n-tile pair in block
    const int kh = w & 1;             // k-half
    const int n = blockIdx.x * 32 + pair * 16 + la;
    const int b = n >> 10, hw = n & 1023;
    const float* zb = z + (size_t)b * (CDIM * 1024) + hw;   // + c*1024

    // B-fragments: m = -2z in fp16 (exact -2z in fp32, then RNE fp16).
    // psum = lane partial sum of z^2 (for THR only).
    f16x8 mh0, mh1;
    float psum = 0.0f;
#pragma unroll
    for (int j = 0; j < 8; ++j) {
        {   float zc = zb[(g * 8 + j) * 1024];
            mh0[j] = (_Float16)(-2.0f * zc);
            psum = fmaf(zc, zc, psum); }
        {   float zc = zb[(32 + g * 8 + j) * 1024];
            mh1[j] = (_Float16)(-2.0f * zc);
            psum = fmaf(zc, zc, psum); }
    }

    unsigned u1k = 0xFFFFFFFFu, u2k = 0xFFFFFFFFu;
    const int kv = g * 4;                          // D-row base for this lane
    const _Float16* tbase = cbT + (size_t)l * 8;   // lane offset inside each sub-block

    // single-slot k-loop: 3 loads -> 2 MFMA -> 4 packed top-2 inserts per 16-k tile.
    // (no ping-pong: live set must stay < 64 VGPR for 8 waves/EU; TLP hides latency)
    const int t0 = kh * 32;
    for (int tt = t0; tt < t0 + 32; ++tt) {
        const _Float16* p_ = tbase + (size_t)tt * 1024;
        const f16x8 ah0 = *(const f16x8*)(p_);
        const f16x8 ah1 = *(const f16x8*)(p_ + 512);
        f32x4 acc = *(const f32x4*)(se16 + tt * 16 + kv);
        acc = __builtin_amdgcn_mfma_f32_16x16x32_f16(ah0, mh0, acc, 0, 0, 0);
        acc = __builtin_amdgcn_mfma_f32_16x16x32_f16(ah1, mh1, acc, 0, 0, 0);
        const int k0 = tt * 16 + kv;
#pragma unroll
        for (int r_ = 0; r_ < 4; ++r_) {
            unsigned ub = __float_as_uint(acc[r_]);
            ub = ((int)ub < 0) ? ~ub : (ub | 0x80000000u);
            const unsigned key = (ub & 0xFFFFFC00u) | (unsigned)(k0 + r_);
            const unsigned mx = (u1k > key) ? u1k : key;
            u1k = (u1k < key) ? u1k : key;
            u2k = (u2k < mx) ? u2k : mx;
        }
    }

    // wave-level exact top-2 + full sum(z^2) across the 4 same-n lane groups
#pragma unroll
    for (int off = 16; off <= 32; off <<= 1) {
        const unsigned p1 = __shfl_xor(u1k, off);
        const unsigned p2 = __shfl_xor(u2k, off);
        psum += __shfl_xor(psum, off);
        const unsigned mx = (u1k > p1) ? u1k : p1;
        u1k = (u1k < p1) ? u1k : p1;
        const unsigned mm = (u2k < p2) ? u2k : p2;
        u2k = (mm < mx) ? mm : mx;
    }

    if (l < 16) { m1[w][la] = u1k; m2[w][la] = u2k; }
    __syncthreads();

    if (kh == 0 && l < 16) {
        // merge with partner k-half (exact top-2-of-disjoint-subsets merge)
        const unsigned o1 = m1[w + 1][la], o2 = m2[w + 1][la];
        const unsigned mx = (u1k > o1) ? u1k : o1;
        const unsigned u1 = (u1k < o1) ? u1k : o1;
        unsigned u2 = (u2k < o2) ? u2k : o2;
        u2 = (u2 < mx) ? u2 : mx;

        const float sx = psum;
        const float srt = sqrtf(fmaxf(fmaxf(semax4[0], semax4[1]),
                                      fmaxf(semax4[2], semax4[3]))) * 1.0001f;
        // worst-case deviation bound (scaled x2^14 space), x1.25 slack (r5-validated)
        const float THR = 60.2f * sqrtf(sx) * srt + 1.97e-2f * sx + 0.165f;
        const unsigned x1 = u1 & 0xFFFFFC00u, x2 = u2 & 0xFFFFFC00u;
        const float f1 = __uint_as_float((x1 & 0x80000000u) ? (x1 & 0x7FFFFFFFu) : ~x1);
        const float f2 = __uint_as_float((x2 & 0x80000000u) ? (x2 & 0x7FFFFFFFu) : ~x2);
        const int k1 = (int)(u1 & 1023u);
        if (f2 - f1 > THR) {     // unique exact argmin guaranteed
            result[n] = (unsigned)k1;
            outIdxF[n] = (float)k1;
            atomicAdd(&hist[k1], 1);
        } else {
            const unsigned widx = atomicAdd(wcount, 1u);
            wlist[widx] = (unsigned)n;
        }
    }
}

// Exact full 1024-k search for flagged n.  Block per 4 worklist items, grid-stride.
// zx/sx staged in LDS (bit-identical reference chain).  Thread owns k=chunk*256+tid
// (4 chunks): cbt[c*1024+k] reads are lane-contiguous (coalesced, L2-hot).
// u64 ordered-key (d bits || k) min -> first-min semantics.
__launch_bounds__(256)
__global__ void rescore2_kernel(const float* __restrict__ z, const float* __restrict__ cbt,
                                const float* __restrict__ se,
                                const unsigned* __restrict__ wlist,
                                const unsigned* __restrict__ wcount,
                                unsigned* __restrict__ result, int* __restrict__ hist,
                                float* __restrict__ outIdxF) {
    __shared__ float zxs[4][64];
    __shared__ float rres[4][8];
    __shared__ float sxs[4];
    __shared__ unsigned long long red[4][4];   // [wave][n-slot]
    const int cnt = (int)*wcount;
    const int tid = threadIdx.x;
    const int wv = tid >> 6, l = tid & 63;

    for (int base = blockIdx.x * 4; base < cnt; base += gridDim.x * 4) {
        // ---- stage z (thread = ns*64 + c) ----
        const int ns = tid >> 6, c = tid & 63;
        const int item = base + ns;
        const int n = (int)wlist[(item < cnt) ? item : base];   // dup-safe tail
        {
            const int b = n >> 10, hw = n & 1023;
            const float zc = z[(size_t)b * (CDIM * 1024) + c * 1024 + hw];
            zxs[ns][c] = zc + zc;                // exact 2z
        }
        __syncthreads();
        if (c < 8) {                             // 8 residue chains (ref-exact)
            const float z0 = zxs[ns][c] * 0.5f;  // exact recover z
            float rr = __fmul_rn(z0, z0);
            for (int i = c + 8; i < 64; i += 8) {
                const float zi = zxs[ns][i] * 0.5f;
                rr = __fadd_rn(rr, __fmul_rn(zi, zi));
            }
            rres[ns][c] = rr;
        }
        __syncthreads();
        if (c == 0) {
            const float* r = rres[ns];
            sxs[ns] = __fadd_rn(__fadd_rn(__fadd_rn(r[0], r[1]), __fadd_rn(r[2], r[3])),
                                __fadd_rn(__fadd_rn(r[4], r[5]), __fadd_rn(r[6], r[7])));
        }
        __syncthreads();

        // ---- k sweep: thread owns k = chunk*256 + tid ----
        unsigned long long best0 = ~0ull, best1 = ~0ull, best2 = ~0ull, best3 = ~0ull;
        for (int chunk = 0; chunk < 4; ++chunk) {       // NOT unrolled: bounded live set
            const int k = (chunk << 8) + tid;
            float a0 = 0.f, a1 = 0.f, a2 = 0.f, a3 = 0.f;
#pragma unroll 2
            for (int c4 = 0; c4 < 16; ++c4) {
                const float e0 = cbt[(4 * c4 + 0) * 1024 + k];   // lane-contiguous
                const float e1 = cbt[(4 * c4 + 1) * 1024 + k];
                const float e2 = cbt[(4 * c4 + 2) * 1024 + k];
                const float e3 = cbt[(4 * c4 + 3) * 1024 + k];
                const f32x4 z0 = *(const f32x4*)&zxs[0][4 * c4]; // LDS broadcast
                const f32x4 z1 = *(const f32x4*)&zxs[1][4 * c4];
                const f32x4 z2 = *(const f32x4*)&zxs[2][4 * c4];
                const f32x4 z3 = *(const f32x4*)&zxs[3][4 * c4];
                a0 = fmaf(z0[0], e0, a0); a0 = fmaf(z0[1], e1, a0);
                a0 = fmaf(z0[2], e2, a0); a0 = fmaf(z0[3], e3, a0);
                a1 = fmaf(z1[0], e0, a1); a1 = fmaf(z1[1], e1, a1);
                a1 = fmaf(z1[2], e2, a1); a1 = fmaf(z1[3], e3, a1);
                a2 = fmaf(z2[0], e0, a2); a2 = fmaf(z2[1], e1, a2);
                a2 = fmaf(z2[2], e2, a2); a2 = fmaf(z2[3], e3, a2);
                a3 = fmaf(z3[0], e0, a3); a3 = fmaf(z3[1], e1, a3);
                a3 = fmaf(z3[2], e2, a3); a3 = fmaf(z3[3], e3, a3);
            }
            const float sek = se[k];
#define DKEY(ai, bi) { const float d_ = __fsub_rn(__fadd_rn(sxs[bi], sek), ai);    \
        unsigned ob = __float_as_uint(d_);                                         \
        ob = (ob & 0x80000000u) ? ~ob : (ob | 0x80000000u);                        \
        const unsigned long long key = ((unsigned long long)ob << 32) | (unsigned)k; \
        if (key < best##bi) best##bi = key; }
            DKEY(a0, 0) DKEY(a1, 1) DKEY(a2, 2) DKEY(a3, 3)
#undef DKEY
        }

        // ---- reduce: per n-slot u64 key min (wave shfl, then cross-wave LDS) ----
#define WRED(bi) {                                                       \
        unsigned long long b_ = best##bi;                                \
        _Pragma("unroll")                                                \
        for (int off = 1; off <= 32; off <<= 1) {                        \
            const unsigned long long o = __shfl_xor(b_, off);            \
            if (o < b_) b_ = o;                                          \
        }                                                                \
        if (l == 0) red[wv][bi] = b_; }
        WRED(0) WRED(1) WRED(2) WRED(3)
#undef WRED
        __syncthreads();
        if (tid < 4 && base + tid < cnt) {
            unsigned long long bb = red[0][tid];
            if (red[1][tid] < bb) bb = red[1][tid];
            if (red[2][tid] < bb) bb = red[2][tid];
            if (red[3][tid] < bb) bb = red[3][tid];
            const int n2 = (int)wlist[base + tid];
            const int kb = (int)(bb & 0xFFFFFFFFull);
            result[n2] = (unsigned)kb;
            outIdxF[n2] = (float)kb;
            atomicAdd(&hist[kb], 1);
        }
        __syncthreads();   // protect zxs/red before next group iteration
    }
}

// quantized_z = cb[idx]; quantized_z_st = fl(z + fl(q - z)); float4-vectorized.
// Block 0 computes perplexity (hist complete: approx+rescore2 finished, stream order).
__global__ void scatter_kernel(const float* __restrict__ z, const float* __restrict__ cb,
                               const unsigned* __restrict__ result,
                               const int* __restrict__ hist,
                               float* __restrict__ out) {
    const int o = (blockIdx.x * 256 + threadIdx.x) * 4;    // [0, NTOT), step 4
    const int b = o >> 16, c = (o >> 10) & 63, hw = o & 1023;
    const int n = (b << 10) | hw;
    float q[4];
#pragma unroll
    for (int j = 0; j < 4; ++j) {
        const int k = (int)result[n + j];
        q[j] = cb[k * CDIM + c];
    }
    const float4 zv = *(const float4*)(z + o);
    *(float4*)(out + o) = make_float4(q[0], q[1], q[2], q[3]);
    float4 st;
    st.x = __fadd_rn(zv.x, __fsub_rn(q[0], zv.x));
    st.y = __fadd_rn(zv.y, __fsub_rn(q[1], zv.y));
    st.z = __fadd_rn(zv.z, __fsub_rn(q[2], zv.z));
    st.w = __fadd_rn(zv.w, __fsub_rn(q[3], zv.w));
    *(float4*)(out + NTOT + o) = st;

    if (blockIdx.x == 0) {
        __shared__ double partial[4];
        const int t = threadIdx.x;        // 256 threads x 4 hist entries
        double term = 0.0;
#pragma unroll
        for (int j = 0; j < 4; ++j) {
            const int cnt = hist[t + 256 * j];
            if (cnt > 0) { const double p = (double)cnt / (double)NVEC; term += p * log(p); }
        }
        for (int off = 32; off > 0; off >>= 1) term += __shfl_down(term, off);
        if ((t & 63) == 0) partial[t >> 6] = term;
        __syncthreads();
        if (t == 0) {
            const double sm = partial[0] + partial[1] + partial[2] + partial[3];
            out[2 * NTOT + NVEC] = (float)exp(-sm);
        }
    }
}

extern "C" void kernel_launch(void* const* d_in, const int* in_sizes, int n_in,
                              void* d_out, int out_size, void* d_ws, size_t ws_size,
                              hipStream_t stream) {
    const float* z  = (const float*)d_in[0];   // [64,64,32,32]
    const float* cb = (const float*)d_in[1];   // [1024,64]
    float* out = (float*)d_out;

    char* ws = (char*)d_ws;
    unsigned* result = (unsigned*)ws;                      // 256 KB
    float* se   = (float*)(ws + 524288);
    int*   hist = (int*)(ws + 528384);

    // Transient scratch inside d_out's quantized_z region (overwritten by scatter later).
    char* outB = (char*)d_out;
    _Float16* cbT   = (_Float16*)(outB + (1 << 20));       // 128 KB
    unsigned* wcount = (unsigned*)(outB + 1572864);
    float*    semax4 = (float*)(outB + 1572864 + 16);
    float*    se16   = (float*)(outB + 1572864 + 4096);    // 4 KB
    unsigned* wlist  = (unsigned*)(outB + (2 << 20));      // 256 KB
    float*    cbt    = (float*)(outB + (2 << 20) + (512 << 10));   // 256 KB @out+2.5MB

    float* outIdxF = out + 2 * NTOT;

    prep_kernel<<<4, 256, 0, stream>>>(cb, se, hist, cbT, se16, semax4, wcount, cbt);
    approx_kernel<<<NVEC / 32, 256, 0, stream>>>(z, cbT, se16, semax4, result, wlist,
                                                 wcount, outIdxF, hist);
    rescore2_kernel<<<1024, 256, 0, stream>>>(z, cbt, se, wlist, wcount, result,
                                              hist, outIdxF);
    scatter_kernel<<<NTOT / 1024, 256, 0, stream>>>(z, cb, result, hist, out);
}

// Round 11
// 166.839 us; speedup vs baseline: 1.1293x; 1.1293x over previous
//
#include <hip/hip_runtime.h>
#include <math.h>

// Problem constants
#define NVEC   65536      // B*H*W
#define CDIM   64
#define KBOOK  1024
#define NTOT   4194304    // B*C*H*W

// d_out layout (float32): [quantized_z: NTOT][quantized_z_st: NTOT][indices: NVEC][perplexity: 1]
// workspace: result u32[NVEC] @0 (256KB) ; float se[KBOOK] @524288 ; int hist[KBOOK] @528384
// TRANSIENT scratch in d_out's quantized_z region (read only BEFORE scatter overwrites):
//   cbT fp16[64 tiles][1024] @out+1MB (128KB) -- fragment-ordered, e scaled x2^14
//   aux @out+1.5MB: wcount u32 @+0 ; semax4 f32[4] @+16 ; se16 f32[1024] @+4096
//   wlist u32[NVEC] @out+2MB (256KB)
//   cbt  f32[64][1024] @out+2.5MB (256KB) -- TRANSPOSED codebook for rescore2
// Ordering: prep -> approx(decisive finalized) -> rescore2(flagged, exact full search)
//           -> scatter(+perp). 4 launches.
//
// ROUND-10 = ROUND-9 RESUBMIT (container infra failure, no counters).  Design:
// arithmetic-intensity fix.  r4-r8 showed schedule tuning at fixed bytes-per-MFMA
// plateaus (r8: 77% of cycles all waves stalled on L2).  Each wave carries 4
// n-tiles' B-fragments (P=4): every 2KB codebook tile load feeds 8 MFMAs + ~100
// VALU of inserts (~240cy issue >= L2 latency, in-wave cover), cbT L2 traffic /4,
// 4 independent insert chains (ILP).  k split 4 ways: the 4 waves of a block are
// the 4 k-splits of one 64-n group; exact 4-way top-2 merge in LDS.
// waves_per_eu(4,4) (the only attr config that never broke).

typedef _Float16 f16x8 __attribute__((ext_vector_type(8)));
typedef float    f32x4 __attribute__((ext_vector_type(4)));

#define FORP(M) M(0) M(1) M(2) M(3)

// prep: zero hist/wcount; exact se (pairwise 8-acc, rn intrinsics); se16 = se*2^14;
// semax4[block] = block-max of se; fragment-ordered fp16 codebook (e*2^14); cbt transpose.
__global__ void prep_kernel(const float* __restrict__ cb, float* __restrict__ se,
                            int* __restrict__ hist, _Float16* __restrict__ cbT,
                            float* __restrict__ se16, float* __restrict__ semax4,
                            unsigned* __restrict__ wcount, float* __restrict__ cbt) {
    __shared__ float lmax[4];
    const int t = blockIdx.x * 256 + threadIdx.x;   // grid 4x256 -> t = codebook row k
    if (t == 0) *wcount = 0u;
    hist[t] = 0;
    const float* row = cb + t * CDIM;
    float r[8];
#pragma unroll
    for (int j = 0; j < 8; ++j) r[j] = __fmul_rn(row[j], row[j]);
#pragma unroll
    for (int i = 8; i < 64; i += 8)
#pragma unroll
        for (int j = 0; j < 8; ++j) r[j] = __fadd_rn(r[j], __fmul_rn(row[i + j], row[i + j]));
    const float sev = __fadd_rn(__fadd_rn(__fadd_rn(r[0], r[1]), __fadd_rn(r[2], r[3])),
                                __fadd_rn(__fadd_rn(r[4], r[5]), __fadd_rn(r[6], r[7])));
    se[t] = sev;
    se16[t] = sev * 16384.0f;            // exact (x2^14)
    float m = sev;
#pragma unroll
    for (int off = 32; off > 0; off >>= 1) m = fmaxf(m, __shfl_xor(m, off));
    if ((threadIdx.x & 63) == 0) lmax[threadIdx.x >> 6] = m;
    __syncthreads();
    if (threadIdx.x == 0)
        semax4[blockIdx.x] = fmaxf(fmaxf(lmax[0], lmax[1]), fmaxf(lmax[2], lmax[3]));
    // transposed codebook for rescore2: cbt[c][k] = cb[k][c]
#pragma unroll
    for (int c = 0; c < 64; ++c) cbt[c * 1024 + t] = row[c];
    // fragment-ordered fp16 codebook, scaled: sub[lane*8+j] = fl16(e*2^14)
    const int tt = t >> 4, la = t & 15;
    _Float16* tb = cbT + (size_t)tt * 1024;        // 2KB tile block (fp16 units)
#pragma unroll
    for (int g = 0; g < 4; ++g)
#pragma unroll
        for (int j = 0; j < 8; ++j) {
            const float e0 = row[8 * g + j] * 16384.0f;        // c in [0,32)
            const float e1 = row[32 + 8 * g + j] * 16384.0f;   // c in [32,64)
            const int lo8 = (g * 16 + la) * 8 + j;             // lane*8 + j
            tb[lo8]       = (_Float16)e0;                      // ah0
            tb[512 + lo8] = (_Float16)e1;                      // ah1
        }
}

// MFMA approx + margin filter.  Block = 64 consecutive n (4 n-tiles); wave w of the
// block = k-split w (16 tiles of 16 k).  Each wave holds 4 n-tiles' B-fragments and
// sweeps its k-range once: per 2KB tile load -> 8 MFMA + 16 packed top-2 inserts.
// Wave butterfly (xor16/32) -> per-(p,la) top-2; LDS merge across the 4 k-split
// waves (exact pairwise merge) -> global top-2 per n.  Decisive -> finalize; else
// worklist.  THR: worst-case |approx-ref| bound (r5-validated, arithmetic identical).
__launch_bounds__(256)
__attribute__((amdgpu_waves_per_eu(4, 4)))
__global__ void approx_kernel(const float* __restrict__ z, const _Float16* __restrict__ cbT,
                              const float* __restrict__ se16, const float* __restrict__ semax4,
                              unsigned* __restrict__ result, unsigned* __restrict__ wlist,
                              unsigned* __restrict__ wcount, float* __restrict__ outIdxF,
                              int* __restrict__ hist) {
    __shared__ unsigned m1[4][4][16], m2[4][4][16];   // [wave][p][la]
    const int tid = threadIdx.x;
    const int w = tid >> 6;           // wave in block = k-split index (0..3)
    const int l = tid & 63;           // lane
    const int la = l & 15;            // D-col (n) offset within tile
    const int g  = l >> 4;            // lane group
    const int nbase = blockIdx.x * 64;

    // B-fragments + psum (sum z^2 over this lane's 16 c, for THR) for 4 n-tiles.
#define ZPRE(p)                                                          \
    f16x8 mh0_##p, mh1_##p; float psum_##p = 0.0f; {                     \
        const int n_ = nbase + (p) * 16 + la;                            \
        const int b_ = n_ >> 10, hw_ = n_ & 1023;                        \
        const float* zb_ = z + (size_t)b_ * (CDIM * 1024) + hw_;         \
        _Pragma("unroll")                                                \
        for (int j = 0; j < 8; ++j) {                                    \
            { float zc = zb_[(g * 8 + j) * 1024];                        \
              mh0_##p[j] = (_Float16)(-2.0f * zc);                       \
              psum_##p = fmaf(zc, zc, psum_##p); }                       \
            { float zc = zb_[(32 + g * 8 + j) * 1024];                   \
              mh1_##p[j] = (_Float16)(-2.0f * zc);                       \
              psum_##p = fmaf(zc, zc, psum_##p); }                       \
        } }
    FORP(ZPRE)
#undef ZPRE

#define KINIT(p) unsigned u1k_##p = 0xFFFFFFFFu, u2k_##p = 0xFFFFFFFFu;
    FORP(KINIT)
#undef KINIT

    const int kv = g * 4;                          // D-row base for this lane
    const _Float16* tbase = cbT + (size_t)l * 8;   // lane offset inside each sub-block

#define DECL_SLOT(s) f16x8 ah0_##s, ah1_##s; f32x4 se_##s;
    DECL_SLOT(a) DECL_SLOT(b)
#undef DECL_SLOT

    // tile-slot load: 2 contiguous 1KB wave-loads + 16B se16 ('& 63' wraps overshoot)
#define LOADT(s, ttv) { const int t_ = (ttv) & 63;                       \
        const _Float16* p_ = tbase + (size_t)t_ * 1024;                  \
        ah0_##s = *(const f16x8*)(p_);                                   \
        ah1_##s = *(const f16x8*)(p_ + 512);                             \
        se_##s  = *(const f32x4*)(se16 + t_ * 16 + kv); }

    // one n-tile's 2 MFMA + 4 packed top-2 inserts (keys: truncated ordered-f32 | k)
#define COMP1(s, p, k0_) {                                               \
        f32x4 acc = se_##s;                                              \
        acc = __builtin_amdgcn_mfma_f32_16x16x32_f16(ah0_##s, mh0_##p, acc, 0, 0, 0); \
        acc = __builtin_amdgcn_mfma_f32_16x16x32_f16(ah1_##s, mh1_##p, acc, 0, 0, 0); \
        _Pragma("unroll")                                                \
        for (int r_ = 0; r_ < 4; ++r_) {                                 \
            unsigned ub = __float_as_uint(acc[r_]);                      \
            ub = ((int)ub < 0) ? ~ub : (ub | 0x80000000u);               \
            const unsigned key = (ub & 0xFFFFFC00u) | (unsigned)((k0_) + r_); \
            const unsigned mx = (u1k_##p > key) ? u1k_##p : key;         \
            u1k_##p = (u1k_##p < key) ? u1k_##p : key;                   \
            u2k_##p = (u2k_##p < mx) ? u2k_##p : mx;                     \
        } }

#define COMPT(s, ttv) { const int k0_ = (ttv) * 16 + kv;                 \
        COMP1(s, 0, k0_) COMP1(s, 1, k0_) COMP1(s, 2, k0_) COMP1(s, 3, k0_) }

    // k-loop: 16 tiles (this wave's k-split), 2-tile ping-pong prefetch
    const int t0 = w * 16;
    LOADT(a, t0)
    for (int tt = t0; tt < t0 + 16; tt += 2) {
        LOADT(b, tt + 1)
        COMPT(a, tt)
        LOADT(a, tt + 2)
        COMPT(b, tt + 1)
    }
#undef LOADT
#undef COMP1
#undef COMPT

    // wave butterfly: exact top-2 + full sum(z^2) across the 4 same-n lane groups
#define BFLY(p) {                                                        \
        _Pragma("unroll")                                                \
        for (int off = 16; off <= 32; off <<= 1) {                       \
            const unsigned p1 = __shfl_xor(u1k_##p, off);                \
            const unsigned p2 = __shfl_xor(u2k_##p, off);                \
            psum_##p += __shfl_xor(psum_##p, off);                       \
            const unsigned mx = (u1k_##p > p1) ? u1k_##p : p1;           \
            u1k_##p = (u1k_##p < p1) ? u1k_##p : p1;                     \
            const unsigned mm = (u2k_##p < p2) ? u2k_##p : p2;           \
            u2k_##p = (mm < mx) ? mm : mx;                               \
        } }
    FORP(BFLY)
#undef BFLY

    if (l < 16) {
#define STOREM(p) m1[w][p][l] = u1k_##p; m2[w][p][l] = u2k_##p;
        FORP(STOREM)
#undef STOREM
    }
    __syncthreads();

    // merger: wave-0 threads tid<64, one per n = nbase + tid.
    if (tid < 64) {
        const int p = tid >> 4, la2 = tid & 15;
        // psum select (register cndmask chain; all wave-0 lanes hold full sums for la2)
        float sx = psum_0;
        if (p == 1) sx = psum_1;
        else if (p == 2) sx = psum_2;
        else if (p == 3) sx = psum_3;
        // exact 4-way top-2 merge of disjoint k-subsets
        unsigned u1 = m1[0][p][la2], u2 = m2[0][p][la2];
#pragma unroll
        for (int ww = 1; ww < 4; ++ww) {
            const unsigned o1 = m1[ww][p][la2], o2 = m2[ww][p][la2];
            const unsigned mx = (u1 > o1) ? u1 : o1;
            u1 = (u1 < o1) ? u1 : o1;
            unsigned t2 = (u2 < o2) ? u2 : o2;
            u2 = (t2 < mx) ? t2 : mx;
        }

        const float srt = sqrtf(fmaxf(fmaxf(semax4[0], semax4[1]),
                                      fmaxf(semax4[2], semax4[3]))) * 1.0001f;
        // worst-case deviation bound (scaled x2^14 space), x1.25 slack (r5-validated)
        const float THR = 60.2f * sqrtf(sx) * srt + 1.97e-2f * sx + 0.165f;
        const unsigned x1 = u1 & 0xFFFFFC00u, x2 = u2 & 0xFFFFFC00u;
        const float f1 = __uint_as_float((x1 & 0x80000000u) ? (x1 & 0x7FFFFFFFu) : ~x1);
        const float f2 = __uint_as_float((x2 & 0x80000000u) ? (x2 & 0x7FFFFFFFu) : ~x2);
        const int k1 = (int)(u1 & 1023u);
        const int n = nbase + tid;
        if (f2 - f1 > THR) {     // unique exact argmin guaranteed
            result[n] = (unsigned)k1;
            outIdxF[n] = (float)k1;
            atomicAdd(&hist[k1], 1);
        } else {
            const unsigned widx = atomicAdd(wcount, 1u);
            wlist[widx] = (unsigned)n;
        }
    }
}

// Exact full 1024-k search for flagged n.  Block per 4 worklist items, grid-stride.
// zx/sx staged in LDS (bit-identical reference chain).  Thread owns k=chunk*256+tid
// (4 chunks): cbt[c*1024+k] reads are lane-contiguous (coalesced, L2-hot).
// u64 ordered-key (d bits || k) min -> first-min semantics.
__launch_bounds__(256)
__global__ void rescore2_kernel(const float* __restrict__ z, const float* __restrict__ cbt,
                                const float* __restrict__ se,
                                const unsigned* __restrict__ wlist,
                                const unsigned* __restrict__ wcount,
                                unsigned* __restrict__ result, int* __restrict__ hist,
                                float* __restrict__ outIdxF) {
    __shared__ float zxs[4][64];
    __shared__ float rres[4][8];
    __shared__ float sxs[4];
    __shared__ unsigned long long red[4][4];   // [wave][n-slot]
    const int cnt = (int)*wcount;
    const int tid = threadIdx.x;
    const int wv = tid >> 6, l = tid & 63;

    for (int base = blockIdx.x * 4; base < cnt; base += gridDim.x * 4) {
        // ---- stage z (thread = ns*64 + c) ----
        const int ns = tid >> 6, c = tid & 63;
        const int item = base + ns;
        const int n = (int)wlist[(item < cnt) ? item : base];   // dup-safe tail
        {
            const int b = n >> 10, hw = n & 1023;
            const float zc = z[(size_t)b * (CDIM * 1024) + c * 1024 + hw];
            zxs[ns][c] = zc + zc;                // exact 2z
        }
        __syncthreads();
        if (c < 8) {                             // 8 residue chains (ref-exact)
            const float z0 = zxs[ns][c] * 0.5f;  // exact recover z
            float rr = __fmul_rn(z0, z0);
            for (int i = c + 8; i < 64; i += 8) {
                const float zi = zxs[ns][i] * 0.5f;
                rr = __fadd_rn(rr, __fmul_rn(zi, zi));
            }
            rres[ns][c] = rr;
        }
        __syncthreads();
        if (c == 0) {
            const float* r = rres[ns];
            sxs[ns] = __fadd_rn(__fadd_rn(__fadd_rn(r[0], r[1]), __fadd_rn(r[2], r[3])),
                                __fadd_rn(__fadd_rn(r[4], r[5]), __fadd_rn(r[6], r[7])));
        }
        __syncthreads();

        // ---- k sweep: thread owns k = chunk*256 + tid ----
        unsigned long long best0 = ~0ull, best1 = ~0ull, best2 = ~0ull, best3 = ~0ull;
        for (int chunk = 0; chunk < 4; ++chunk) {       // NOT unrolled: bounded live set
            const int k = (chunk << 8) + tid;
            float a0 = 0.f, a1 = 0.f, a2 = 0.f, a3 = 0.f;
#pragma unroll 2
            for (int c4 = 0; c4 < 16; ++c4) {
                const float e0 = cbt[(4 * c4 + 0) * 1024 + k];   // lane-contiguous
                const float e1 = cbt[(4 * c4 + 1) * 1024 + k];
                const float e2 = cbt[(4 * c4 + 2) * 1024 + k];
                const float e3 = cbt[(4 * c4 + 3) * 1024 + k];
                const f32x4 z0 = *(const f32x4*)&zxs[0][4 * c4]; // LDS broadcast
                const f32x4 z1 = *(const f32x4*)&zxs[1][4 * c4];
                const f32x4 z2 = *(const f32x4*)&zxs[2][4 * c4];
                const f32x4 z3 = *(const f32x4*)&zxs[3][4 * c4];
                a0 = fmaf(z0[0], e0, a0); a0 = fmaf(z0[1], e1, a0);
                a0 = fmaf(z0[2], e2, a0); a0 = fmaf(z0[3], e3, a0);
                a1 = fmaf(z1[0], e0, a1); a1 = fmaf(z1[1], e1, a1);
                a1 = fmaf(z1[2], e2, a1); a1 = fmaf(z1[3], e3, a1);
                a2 = fmaf(z2[0], e0, a2); a2 = fmaf(z2[1], e1, a2);
                a2 = fmaf(z2[2], e2, a2); a2 = fmaf(z2[3], e3, a2);
                a3 = fmaf(z3[0], e0, a3); a3 = fmaf(z3[1], e1, a3);
                a3 = fmaf(z3[2], e2, a3); a3 = fmaf(z3[3], e3, a3);
            }
            const float sek = se[k];
#define DKEY(ai, bi) { const float d_ = __fsub_rn(__fadd_rn(sxs[bi], sek), ai);    \
        unsigned ob = __float_as_uint(d_);                                         \
        ob = (ob & 0x80000000u) ? ~ob : (ob | 0x80000000u);                        \
        const unsigned long long key = ((unsigned long long)ob << 32) | (unsigned)k; \
        if (key < best##bi) best##bi = key; }
            DKEY(a0, 0) DKEY(a1, 1) DKEY(a2, 2) DKEY(a3, 3)
#undef DKEY
        }

        // ---- reduce: per n-slot u64 key min (wave shfl, then cross-wave LDS) ----
#define WRED(bi) {                                                       \
        unsigned long long b_ = best##bi;                                \
        _Pragma("unroll")                                                \
        for (int off = 1; off <= 32; off <<= 1) {                        \
            const unsigned long long o = __shfl_xor(b_, off);            \
            if (o < b_) b_ = o;                                          \
        }                                                                \
        if (l == 0) red[wv][bi] = b_; }
        WRED(0) WRED(1) WRED(2) WRED(3)
#undef WRED
        __syncthreads();
        if (tid < 4 && base + tid < cnt) {
            unsigned long long bb = red[0][tid];
            if (red[1][tid] < bb) bb = red[1][tid];
            if (red[2][tid] < bb) bb = red[2][tid];
            if (red[3][tid] < bb) bb = red[3][tid];
            const int n2 = (int)wlist[base + tid];
            const int kb = (int)(bb & 0xFFFFFFFFull);
            result[n2] = (unsigned)kb;
            outIdxF[n2] = (float)kb;
            atomicAdd(&hist[kb], 1);
        }
        __syncthreads();   // protect zxs/red before next group iteration
    }
}

// quantized_z = cb[idx]; quantized_z_st = fl(z + fl(q - z)); float4-vectorized.
// Block 0 computes perplexity (hist complete: approx+rescore2 finished, stream order).
__global__ void scatter_kernel(const float* __restrict__ z, const float* __restrict__ cb,
                               const unsigned* __restrict__ result,
                               const int* __restrict__ hist,
                               float* __restrict__ out) {
    const int o = (blockIdx.x * 256 + threadIdx.x) * 4;    // [0, NTOT), step 4
    const int b = o >> 16, c = (o >> 10) & 63, hw = o & 1023;
    const int n = (b << 10) | hw;
    float q[4];
#pragma unroll
    for (int j = 0; j < 4; ++j) {
        const int k = (int)result[n + j];
        q[j] = cb[k * CDIM + c];
    }
    const float4 zv = *(const float4*)(z + o);
    *(float4*)(out + o) = make_float4(q[0], q[1], q[2], q[3]);
    float4 st;
    st.x = __fadd_rn(zv.x, __fsub_rn(q[0], zv.x));
    st.y = __fadd_rn(zv.y, __fsub_rn(q[1], zv.y));
    st.z = __fadd_rn(zv.z, __fsub_rn(q[2], zv.z));
    st.w = __fadd_rn(zv.w, __fsub_rn(q[3], zv.w));
    *(float4*)(out + NTOT + o) = st;

    if (blockIdx.x == 0) {
        __shared__ double partial[4];
        const int t = threadIdx.x;        // 256 threads x 4 hist entries
        double term = 0.0;
#pragma unroll
        for (int j = 0; j < 4; ++j) {
            const int cnt = hist[t + 256 * j];
            if (cnt > 0) { const double p = (double)cnt / (double)NVEC; term += p * log(p); }
        }
        for (int off = 32; off > 0; off >>= 1) term += __shfl_down(term, off);
        if ((t & 63) == 0) partial[t >> 6] = term;
        __syncthreads();
        if (t == 0) {
            const double sm = partial[0] + partial[1] + partial[2] + partial[3];
            out[2 * NTOT + NVEC] = (float)exp(-sm);
        }
    }
}

extern "C" void kernel_launch(void* const* d_in, const int* in_sizes, int n_in,
                              void* d_out, int out_size, void* d_ws, size_t ws_size,
                              hipStream_t stream) {
    const float* z  = (const float*)d_in[0];   // [64,64,32,32]
    const float* cb = (const float*)d_in[1];   // [1024,64]
    float* out = (float*)d_out;

    char* ws = (char*)d_ws;
    unsigned* result = (unsigned*)ws;                      // 256 KB
    float* se   = (float*)(ws + 524288);
    int*   hist = (int*)(ws + 528384);

    // Transient scratch inside d_out's quantized_z region (overwritten by scatter later).
    char* outB = (char*)d_out;
    _Float16* cbT   = (_Float16*)(outB + (1 << 20));       // 128 KB
    unsigned* wcount = (unsigned*)(outB + 1572864);
    float*    semax4 = (float*)(outB + 1572864 + 16);
    float*    se16   = (float*)(outB + 1572864 + 4096);    // 4 KB
    unsigned* wlist  = (unsigned*)(outB + (2 << 20));      // 256 KB
    float*    cbt    = (float*)(outB + (2 << 20) + (512 << 10));   // 256 KB @out+2.5MB

    float* outIdxF = out + 2 * NTOT;

    prep_kernel<<<4, 256, 0, stream>>>(cb, se, hist, cbT, se16, semax4, wcount, cbt);
    approx_kernel<<<NVEC / 64, 256, 0, stream>>>(z, cbT, se16, semax4, result, wlist,
                                                 wcount, outIdxF, hist);
    rescore2_kernel<<<1024, 256, 0, stream>>>(z, cbt, se, wlist, wcount, result,
                                              hist, outIdxF);
    scatter_kernel<<<NTOT / 1024, 256, 0, stream>>>(z, cb, result, hist, out);
}